// Round 10
// baseline (253.767 us; speedup 1.0000x reference)
//
#include <hip/hip_runtime.h>
#include <math.h>

#define BB 2
#define LL 2048
#define DM 192
#define DI 384
#define DS 16
#define RK 12
#define NROW (BB*LL)      // 4096
#define NCH 64
#define CLEN (LL/NCH)     // 32
#define CSTILE 32

typedef __attribute__((ext_vector_type(8))) short bf16x8;
typedef __attribute__((ext_vector_type(4))) float f32x4;

__device__ __forceinline__ float siluf(float v) { return v / (1.f + __expf(-v)); }

__device__ __forceinline__ unsigned short f2bf(float f) {
  unsigned int x = __float_as_uint(f);
  unsigned int r = (x + 0x7fffu + ((x >> 16) & 1u)) >> 16;
  return (unsigned short)r;
}
__device__ __forceinline__ float bf2f(unsigned short u) {
  return __uint_as_float(((unsigned int)u) << 16);
}

// ---------------- K0: weight pack (MFMA fragment order) + rmsnorm fused -----
#define N_BFIN  (6*48*512)      // 147456
#define N_BFOUT (12*12*512)     // 73728
#define N_BFXP  (2*12*4*512)    // 49152
#define N_DT    (2*RK*DI)       // 9216
#define N_PREP  (N_BFIN + N_BFOUT + N_BFXP + N_DT)   // 279552 = 1092*256
#define PREP_BLKS 1092

__global__ __launch_bounds__(256) void k_prep(
    const float* __restrict__ wip, const float* __restrict__ wop,
    const float* __restrict__ xpwf, const float* __restrict__ xpwb,
    const float* __restrict__ dtwf, const float* __restrict__ dtwb,
    unsigned short* __restrict__ bin, unsigned short* __restrict__ bout,
    unsigned short* __restrict__ bxp, float* __restrict__ wdt,
    const float* __restrict__ h, const float* __restrict__ r,
    const float* __restrict__ w, float* __restrict__ res,
    unsigned short* __restrict__ xnb) {
  int blk = blockIdx.x;
  if (blk < PREP_BLKS) {
    int i = blk * 256 + threadIdx.x;
    if (i < N_BFIN) {
      int j = i & 7, l = (i >> 3) & 63, ng = (i >> 9) % 48, ks = i / (48 * 512);
      int k = ks * 32 + (l >> 4) * 8 + j, c = ng * 16 + (l & 15);
      bin[i] = f2bf(wip[c * DM + k]);
    } else if (i < N_BFIN + N_BFOUT) {
      int t = i - N_BFIN;
      int j = t & 7, l = (t >> 3) & 63, ng = (t >> 9) % 12, ks = t / (12 * 512);
      int k = ks * 32 + (l >> 4) * 8 + j, c = ng * 16 + (l & 15);
      bout[t] = f2bf(wop[c * DI + k]);
    } else if (i < N_BFIN + N_BFOUT + N_BFXP) {
      int t = i - N_BFIN - N_BFOUT;
      int j = t & 7, l = (t >> 3) & 63, ng = (t >> 9) & 3, ks = (t >> 11) % 12;
      int dir = t / (12 * 4 * 512);
      int k = ks * 32 + (l >> 4) * 8 + j, e = ng * 16 + (l & 15);
      const float* src = dir ? xpwb : xpwf;
      bxp[t] = (e < RK + 2 * DS) ? f2bf(src[e * DI + k]) : (unsigned short)0;
    } else if (i < N_PREP) {
      int t = i - N_BFIN - N_BFOUT - N_BFXP;
      int dir = t / (RK * DI), rem = t % (RK * DI);
      int j = rem / DI, d = rem % DI;
      const float* src = dir ? dtwb : dtwf;
      wdt[t] = src[d * RK + j];
    }
  } else {
    int row = (blk - PREP_BLKS) * 4 + (threadIdx.x >> 6);
    int lane = threadIdx.x & 63;
    const float* hp = h + row * DM;
    const float* rp = r + row * DM;
    float v0 = hp[lane]       + rp[lane];
    float v1 = hp[lane + 64]  + rp[lane + 64];
    float v2 = hp[lane + 128] + rp[lane + 128];
    float ss = v0 * v0 + v1 * v1 + v2 * v2;
    #pragma unroll
    for (int o = 32; o; o >>= 1) ss += __shfl_xor(ss, o);
    float inv = rsqrtf(ss * (1.f / DM) + 1e-5f);
    float* rr = res + row * DM;
    unsigned short* xo = xnb + row * DM;
    rr[lane] = v0; rr[lane + 64] = v1; rr[lane + 128] = v2;
    xo[lane]       = f2bf(v0 * inv * w[lane]);
    xo[lane + 64]  = f2bf(v1 * inv * w[lane + 64]);
    xo[lane + 128] = f2bf(v2 * inv * w[lane + 128]);
  }
}

// ---------------- K2: in_proj via MFMA -> bf16 xhb, zb ----------------
__global__ __launch_bounds__(64) void k_inproj(
    const unsigned short* __restrict__ xnb, const unsigned short* __restrict__ bin,
    unsigned short* __restrict__ xhb, unsigned short* __restrict__ zb) {
  int l = threadIdx.x;
  int row0 = blockIdx.x * 16;
  int ng0 = blockIdx.y * 4;
  const unsigned short* arow = xnb + (size_t)(row0 + (l & 15)) * DM + ((l >> 4) * 8);
  f32x4 acc[4];
  #pragma unroll
  for (int g = 0; g < 4; g++) acc[g] = (f32x4){0.f, 0.f, 0.f, 0.f};
  #pragma unroll
  for (int ks = 0; ks < 6; ks++) {
    bf16x8 a = *reinterpret_cast<const bf16x8*>(arow + ks * 32);
    #pragma unroll
    for (int g = 0; g < 4; g++) {
      bf16x8 b = *reinterpret_cast<const bf16x8*>(bin + ((size_t)(ks * 48 + ng0 + g) * 64 + l) * 8);
      acc[g] = __builtin_amdgcn_mfma_f32_16x16x32_bf16(a, b, acc[g], 0, 0, 0);
    }
  }
  int rbase = row0 + (l >> 4) * 4;
  #pragma unroll
  for (int g = 0; g < 4; g++) {
    int col = (ng0 + g) * 16 + (l & 15);
    unsigned short* dst = (col < DI) ? (xhb + col) : (zb + (col - DI));
    #pragma unroll
    for (int r = 0; r < 4; r++) dst[(size_t)(rbase + r) * DI] = f2bf(acc[g][r]);
  }
}

// ---------------- K3: conv + SiLU -> xcb (row-major) + xcT (chain-major) ----
__global__ __launch_bounds__(256) void k_conv(
    const unsigned short* __restrict__ xhb,
    const float* __restrict__ cwf, const float* __restrict__ cbf,
    const float* __restrict__ cwb, const float* __restrict__ cbb,
    unsigned short* __restrict__ xcb, unsigned short* __restrict__ xcT) {
  __shared__ unsigned short tile[DI][CSTILE + 4];   // stride 36 ushort = 72 B
  int zbi = blockIdx.y;               // dir*2 + b
  int dir = zbi >> 1, b = zbi & 1;
  int s0 = blockIdx.x * CSTILE;
  const float* cw = dir ? cwb : cwf;
  const float* cb = dir ? cbb : cbf;
  for (int o = threadIdx.x; o < DI * CSTILE; o += 256) {
    int d = o % DI;                   // consecutive threads -> consecutive d
    int s = o / DI;
    int sg = s0 + s;
    float acc = cb[d];
    #pragma unroll
    for (int k = 0; k < 4; k++) {
      int sp = sg - 3 + k;
      if (sp >= 0) {
        int mr = b * LL + (dir ? (LL - 1 - sp) : sp);
        acc += cw[d * 4 + k] * bf2f(xhb[(size_t)mr * DI + d]);
      }
    }
    unsigned short v = f2bf(siluf(acc));
    xcb[(size_t)(zbi * LL + sg) * DI + d] = v;
    tile[d][s] = v;
  }
  __syncthreads();
  for (int o = threadIdx.x; o < DI * (CSTILE / 4); o += 256) {
    int q = o & 7, d = o >> 3;        // 8 lanes cover one d's 32 s
    ushort4 v = *reinterpret_cast<const ushort4*>(&tile[d][q * 4]);
    *reinterpret_cast<ushort4*>(xcT + ((size_t)(zbi * DI) + d) * LL + s0 + q * 4) = v;
  }
}

// ---------------- K4: x_proj MFMA + dt(->dtT chain-major)/B/C fused ---------
__global__ __launch_bounds__(128) void k_xpmm(
    const unsigned short* __restrict__ xcb, const unsigned short* __restrict__ bxp,
    const float* __restrict__ wdt_all,
    const float* __restrict__ dtbf, const float* __restrict__ dtbb,
    float* __restrict__ dtT, float* __restrict__ Bm, float* __restrict__ Cm) {
  __shared__ float xd[16][48];
  int l = threadIdx.x & 63, w = threadIdx.x >> 6;
  int dir = blockIdx.y;
  int row0 = blockIdx.x * 16;
  const unsigned short* arow = xcb + (size_t)(dir * NROW + row0 + (l & 15)) * DI + ((l >> 4) * 8);
  const unsigned short* wb = bxp + (size_t)dir * 12 * 4 * 512;
  f32x4 acc[2];
  acc[0] = (f32x4){0.f, 0.f, 0.f, 0.f};
  acc[1] = (f32x4){0.f, 0.f, 0.f, 0.f};
  #pragma unroll
  for (int ks = 0; ks < 12; ks++) {
    bf16x8 a = *reinterpret_cast<const bf16x8*>(arow + ks * 32);
    #pragma unroll
    for (int g = 0; g < 2; g++) {
      int ng = w * 2 + g;
      bf16x8 b = *reinterpret_cast<const bf16x8*>(wb + ((size_t)(ks * 4 + ng) * 64 + l) * 8);
      acc[g] = __builtin_amdgcn_mfma_f32_16x16x32_bf16(a, b, acc[g], 0, 0, 0);
    }
  }
  int rbase = (l >> 4) * 4;
  #pragma unroll
  for (int g = 0; g < 2; g++) {
    int col = (w * 2 + g) * 16 + (l & 15);
    #pragma unroll
    for (int r = 0; r < 4; r++) xd[rbase + r][col] = acc[g][r];
  }
  __syncthreads();
  const float* wdt = wdt_all + dir * RK * DI;
  const float* dtb = dir ? dtbb : dtbf;
  int t = threadIdx.x;
  int b = row0 >> 11, sloc = row0 & (LL - 1);
  int zbi = dir * 2 + b;
  // dt phase: each thread owns 3 d's, computes 16 s values, writes 64B runs
  #pragma unroll
  for (int dd = 0; dd < 3; dd++) {
    int d = dd * 128 + t;
    float bias = dtb[d];
    float a[16];
    #pragma unroll
    for (int r = 0; r < 16; r++) {
      float acc2 = bias;
      #pragma unroll
      for (int j = 0; j < RK; j++) acc2 = __fmaf_rn(xd[r][j], wdt[j * DI + d], acc2);
      a[r] = (acc2 > 20.f) ? acc2 : log1pf(__expf(acc2));
    }
    float* dst = dtT + ((size_t)(zbi * DI) + d) * LL + sloc;
    #pragma unroll
    for (int q = 0; q < 4; q++)
      *reinterpret_cast<float4*>(dst + q * 4) =
          make_float4(a[q*4], a[q*4+1], a[q*4+2], a[q*4+3]);
  }
  // B/C: 16 rows x 32
  #pragma unroll
  for (int i = 0; i < 4; i++) {
    int idx = i * 128 + t;
    int row = idx / 32, j = idx % 32;
    float v = xd[row][RK + j];
    if (j < DS) Bm[(size_t)(dir * NROW + row0 + row) * DS + j] = v;
    else        Cm[(size_t)(dir * NROW + row0 + row) * DS + (j - DS)] = v;
  }
}

// ---------------- S1: per-chunk local scan (chain-major streams) ------------
__global__ __launch_bounds__(128) void k_scan1(
    const float* __restrict__ dtT, const unsigned short* __restrict__ xcT,
    const float* __restrict__ Bm,
    const float* __restrict__ Alf, const float* __restrict__ Alb,
    float* __restrict__ S, float* __restrict__ P) {
  int zb = blockIdx.z;
  int dir = zb >> 1;
  int d = blockIdx.x * 128 + threadIdx.x;
  int c = blockIdx.y;
  const float* Al = dir ? Alb : Alf;
  float Av[DS];
  {
    const float4* ap = reinterpret_cast<const float4*>(Al + d * DS);
    #pragma unroll
    for (int q = 0; q < 4; q++) {
      float4 a = ap[q];
      Av[4*q+0] = -__expf(a.x); Av[4*q+1] = -__expf(a.y);
      Av[4*q+2] = -__expf(a.z); Av[4*q+3] = -__expf(a.w);
    }
  }
  const float4* dt4 = reinterpret_cast<const float4*>(dtT + ((size_t)(zb * DI) + d) * LL + c * CLEN);
  const ushort4* xc4 = reinterpret_cast<const ushort4*>(xcT + ((size_t)(zb * DI) + d) * LL + c * CLEN);
  int rowbase = zb * LL + c * CLEN;
  const float4* Bp4 = reinterpret_cast<const float4*>(Bm + (size_t)rowbase * DS);
  float h[DS];
  #pragma unroll
  for (int n = 0; n < DS; n++) h[n] = 0.f;
  float sdt = 0.f;
  #pragma unroll 2
  for (int s4 = 0; s4 < CLEN / 4; s4++) {
    float4 dq = dt4[s4];
    ushort4 xq = xc4[s4];
    float dts[4] = {dq.x, dq.y, dq.z, dq.w};
    float xs[4]  = {bf2f(xq.x), bf2f(xq.y), bf2f(xq.z), bf2f(xq.w)};
    #pragma unroll
    for (int k = 0; k < 4; k++) {
      int s = s4 * 4 + k;
      float4 B0 = Bp4[s*4+0], B1 = Bp4[s*4+1], B2 = Bp4[s*4+2], B3 = Bp4[s*4+3];
      float Bv[DS] = {B0.x,B0.y,B0.z,B0.w, B1.x,B1.y,B1.z,B1.w,
                      B2.x,B2.y,B2.z,B2.w, B3.x,B3.y,B3.z,B3.w};
      float dtv = dts[k];
      float dtx = dtv * xs[k];
      sdt += dtv;
      #pragma unroll
      for (int n = 0; n < DS; n++) {
        float dA = __expf(dtv * Av[n]);
        h[n] = __fmaf_rn(dA, h[n], dtx * Bv[n]);
      }
    }
  }
  size_t base = ((size_t)(zb * NCH + c) * DI + d) * DS;
  float4* Sp = reinterpret_cast<float4*>(S + base);
  float4* Pp = reinterpret_cast<float4*>(P + base);
  #pragma unroll
  for (int q = 0; q < 4; q++) {
    Sp[q] = make_float4(h[4*q+0], h[4*q+1], h[4*q+2], h[4*q+3]);
    Pp[q] = make_float4(__expf(Av[4*q+0]*sdt), __expf(Av[4*q+1]*sdt),
                        __expf(Av[4*q+2]*sdt), __expf(Av[4*q+3]*sdt));
  }
}

// ---------------- S2: combine carries across chunks (in-place: S -> Hin) ---
__global__ __launch_bounds__(256) void k_scan2(
    float* __restrict__ S, const float* __restrict__ P) {
  int g = blockIdx.x * 256 + threadIdx.x;
  int zb = g / (DI * DS);
  int rem = g % (DI * DS);
  const int stride = DI * DS;
  size_t base = (size_t)zb * NCH * stride + rem;
  float carry = 0.f;
  for (int c0 = 0; c0 < NCH; c0 += 8) {
    float p8[8], s8[8];
    #pragma unroll
    for (int j = 0; j < 8; j++) {
      p8[j] = P[base + (size_t)(c0 + j) * stride];
      s8[j] = S[base + (size_t)(c0 + j) * stride];
    }
    #pragma unroll
    for (int j = 0; j < 8; j++) {
      S[base + (size_t)(c0 + j) * stride] = carry;
      carry = __fmaf_rn(p8[j], carry, s8[j]);
    }
  }
}

// ---------------- S3: final per-chunk scan + y (bf16 out) ----------------
__global__ __launch_bounds__(128) void k_scan3(
    const float* __restrict__ dtT, const unsigned short* __restrict__ xcT,
    const float* __restrict__ Bm, const float* __restrict__ Cm,
    const unsigned short* __restrict__ zb_, const float* __restrict__ Hin,
    const float* __restrict__ Alf, const float* __restrict__ Alb,
    const float* __restrict__ Df, const float* __restrict__ Db,
    unsigned short* __restrict__ yb) {
  int zbi = blockIdx.z;
  int dir = zbi >> 1, b = zbi & 1;
  int d = blockIdx.x * 128 + threadIdx.x;
  int c = blockIdx.y;
  const float* Al = dir ? Alb : Alf;
  const float* Dp = dir ? Db : Df;
  float Av[DS];
  {
    const float4* ap = reinterpret_cast<const float4*>(Al + d * DS);
    #pragma unroll
    for (int q = 0; q < 4; q++) {
      float4 a = ap[q];
      Av[4*q+0] = -__expf(a.x); Av[4*q+1] = -__expf(a.y);
      Av[4*q+2] = -__expf(a.z); Av[4*q+3] = -__expf(a.w);
    }
  }
  float Dv = Dp[d];
  const float4* dt4 = reinterpret_cast<const float4*>(dtT + ((size_t)(zbi * DI) + d) * LL + c * CLEN);
  const ushort4* xc4 = reinterpret_cast<const ushort4*>(xcT + ((size_t)(zbi * DI) + d) * LL + c * CLEN);
  int rowbase = zbi * LL + c * CLEN;
  const float4* Bp4 = reinterpret_cast<const float4*>(Bm + (size_t)rowbase * DS);
  const float4* Cp4 = reinterpret_cast<const float4*>(Cm + (size_t)rowbase * DS);
  size_t base = ((size_t)(zbi * NCH + c) * DI + d) * DS;
  float h[DS];
  {
    const float4* hp = reinterpret_cast<const float4*>(Hin + base);
    #pragma unroll
    for (int q = 0; q < 4; q++) {
      float4 a = hp[q];
      h[4*q+0] = a.x; h[4*q+1] = a.y; h[4*q+2] = a.z; h[4*q+3] = a.w;
    }
  }
  #pragma unroll 2
  for (int s4 = 0; s4 < CLEN / 4; s4++) {
    float4 dq = dt4[s4];
    ushort4 xq = xc4[s4];
    float dts[4] = {dq.x, dq.y, dq.z, dq.w};
    float xs[4]  = {bf2f(xq.x), bf2f(xq.y), bf2f(xq.z), bf2f(xq.w)};
    #pragma unroll
    for (int k = 0; k < 4; k++) {
      int s = s4 * 4 + k;
      float4 B0 = Bp4[s*4+0], B1 = Bp4[s*4+1], B2 = Bp4[s*4+2], B3 = Bp4[s*4+3];
      float Bv[DS] = {B0.x,B0.y,B0.z,B0.w, B1.x,B1.y,B1.z,B1.w,
                      B2.x,B2.y,B2.z,B2.w, B3.x,B3.y,B3.z,B3.w};
      float4 C0 = Cp4[s*4+0], C1 = Cp4[s*4+1], C2 = Cp4[s*4+2], C3 = Cp4[s*4+3];
      float Cv[DS] = {C0.x,C0.y,C0.z,C0.w, C1.x,C1.y,C1.z,C1.w,
                      C2.x,C2.y,C2.z,C2.w, C3.x,C3.y,C3.z,C3.w};
      float dtv = dts[k];
      float xv = xs[k];
      float dtx = dtv * xv;
      float acc = xv * Dv;
      #pragma unroll
      for (int n = 0; n < DS; n++) {
        float dA = __expf(dtv * Av[n]);
        h[n] = __fmaf_rn(dA, h[n], dtx * Bv[n]);
        acc = __fmaf_rn(h[n], Cv[n], acc);
      }
      int sg = c * CLEN + s;
      int mr = b * LL + (dir ? (LL - 1 - sg) : sg);
      float zv = bf2f(zb_[(size_t)mr * DI + d]);
      yb[(size_t)(rowbase + s) * DI + d] = f2bf(acc * siluf(zv));
    }
  }
}

// ---------------- K5: out_proj via MFMA (fused y_f + rev(y_b)) ---------
__global__ __launch_bounds__(64) void k_outproj(
    const unsigned short* __restrict__ yb, const unsigned short* __restrict__ bout,
    float* __restrict__ out) {
  int l = threadIdx.x;
  int row0 = blockIdx.x * 16;
  int ng0 = blockIdx.y * 2;
  int row = row0 + (l & 15);
  int b = row >> 11, ll = row & (LL - 1);
  const unsigned short* yf = yb + (size_t)(b * LL + ll) * DI + (l >> 4) * 8;
  const unsigned short* yr = yb + (size_t)((2 + b) * LL + (LL - 1 - ll)) * DI + (l >> 4) * 8;
  f32x4 acc[2];
  acc[0] = (f32x4){0.f, 0.f, 0.f, 0.f};
  acc[1] = (f32x4){0.f, 0.f, 0.f, 0.f};
  #pragma unroll
  for (int ks = 0; ks < 12; ks++) {
    bf16x8 f8 = *reinterpret_cast<const bf16x8*>(yf + ks * 32);
    bf16x8 g8 = *reinterpret_cast<const bf16x8*>(yr + ks * 32);
    bf16x8 a;
    #pragma unroll
    for (int j = 0; j < 8; j++)
      a[j] = (short)f2bf(bf2f((unsigned short)f8[j]) + bf2f((unsigned short)g8[j]));
    #pragma unroll
    for (int g = 0; g < 2; g++) {
      bf16x8 bb = *reinterpret_cast<const bf16x8*>(bout + ((size_t)(ks * 12 + ng0 + g) * 64 + l) * 8);
      acc[g] = __builtin_amdgcn_mfma_f32_16x16x32_bf16(a, bb, acc[g], 0, 0, 0);
    }
  }
  int rbase = row0 + (l >> 4) * 4;
  #pragma unroll
  for (int g = 0; g < 2; g++) {
    int col = (ng0 + g) * 16 + (l & 15);
    #pragma unroll
    for (int r = 0; r < 4; r++) out[(size_t)(rbase + r) * DM + col] = acc[g][r];
  }
}

extern "C" void kernel_launch(void* const* d_in, const int* in_sizes, int n_in,
                              void* d_out, int out_size, void* d_ws, size_t ws_size,
                              hipStream_t stream) {
  const float* hid  = (const float*)d_in[0];
  const float* res  = (const float*)d_in[1];
  const float* nw   = (const float*)d_in[2];
  const float* wip  = (const float*)d_in[3];
  const float* wop  = (const float*)d_in[4];
  const float* cwf  = (const float*)d_in[5];
  const float* cbf  = (const float*)d_in[6];
  const float* xpwf = (const float*)d_in[7];
  const float* dtwf = (const float*)d_in[8];
  const float* dtbf = (const float*)d_in[9];
  const float* Alf  = (const float*)d_in[10];
  const float* Df   = (const float*)d_in[11];
  const float* cwb  = (const float*)d_in[12];
  const float* cbb  = (const float*)d_in[13];
  const float* xpwb = (const float*)d_in[14];
  const float* dtwb = (const float*)d_in[15];
  const float* dtbb = (const float*)d_in[16];
  const float* Alb  = (const float*)d_in[17];
  const float* Db   = (const float*)d_in[18];

  float* out_p  = (float*)d_out;                  // (B,L,192)
  float* resid  = out_p + NROW * DM;              // (B,L,192)

  float* ws = (float*)d_ws;
  // f32 arrays
  float* dtT  = ws;                          // 2*NROW*DI
  float* Bm   = dtT  + 2 * NROW * DI;        // 2*NROW*DS
  float* Cm   = Bm   + 2 * NROW * DS;
  float* S    = Cm   + 2 * NROW * DS;        // 2*BB*NCH*DI*DS
  float* P    = S    + 2 * BB * NCH * DI * DS;
  float* wdt  = P    + 2 * BB * NCH * DI * DS;   // N_DT
  // bf16 arrays
  unsigned short* xnb = (unsigned short*)(wdt + N_DT);   // NROW*DM
  unsigned short* xhb = xnb + NROW * DM;                 // NROW*DI
  unsigned short* zb  = xhb + NROW * DI;                 // NROW*DI
  unsigned short* xcb = zb  + NROW * DI;                 // 2*NROW*DI
  unsigned short* xcT = xcb + 2 * NROW * DI;             // 2*NROW*DI
  unsigned short* yb  = xcT + 2 * NROW * DI;             // 2*NROW*DI
  unsigned short* bin = yb  + 2 * NROW * DI;             // N_BFIN
  unsigned short* bout = bin + N_BFIN;                   // N_BFOUT
  unsigned short* bxp  = bout + N_BFOUT;                 // N_BFXP

  k_prep<<<PREP_BLKS + NROW / 4, 256, 0, stream>>>(wip, wop, xpwf, xpwb, dtwf, dtwb,
                                                   bin, bout, bxp, wdt,
                                                   hid, res, nw, resid, xnb);
  k_inproj<<<dim3(NROW / 16, 12), 64, 0, stream>>>(xnb, bin, xhb, zb);
  k_conv<<<dim3(LL / CSTILE, 2 * BB), 256, 0, stream>>>(xhb, cwf, cbf, cwb, cbb, xcb, xcT);
  k_xpmm<<<dim3(NROW / 16, 2), 128, 0, stream>>>(xcb, bxp, wdt, dtbf, dtbb, dtT, Bm, Cm);
  k_scan1<<<dim3(DI / 128, NCH, 2 * BB), 128, 0, stream>>>(dtT, xcT, Bm, Alf, Alb, S, P);
  k_scan2<<<(2 * BB * DI * DS) / 256, 256, 0, stream>>>(S, P);
  k_scan3<<<dim3(DI / 128, NCH, 2 * BB), 128, 0, stream>>>(dtT, xcT, Bm, Cm, zb, S,
                                                           Alf, Alb, Df, Db, yb);
  k_outproj<<<dim3(NROW / 16, 6), 64, 0, stream>>>(yb, bout, out_p);
}

// Round 11
// 224.597 us; speedup vs baseline: 1.1299x; 1.1299x over previous
//
#include <hip/hip_runtime.h>
#include <math.h>

#define BB 2
#define LL 2048
#define DM 192
#define DI 384
#define DS 16
#define RK 12
#define NROW (BB*LL)      // 4096
#define NCH 64
#define CLEN (LL/NCH)     // 32
#define CSTILE 32
#define CD 128            // conv d-tile

typedef __attribute__((ext_vector_type(8))) short bf16x8;
typedef __attribute__((ext_vector_type(4))) float f32x4;

__device__ __forceinline__ float siluf(float v) { return v / (1.f + __expf(-v)); }

__device__ __forceinline__ unsigned short f2bf(float f) {
  unsigned int x = __float_as_uint(f);
  unsigned int r = (x + 0x7fffu + ((x >> 16) & 1u)) >> 16;
  return (unsigned short)r;
}
__device__ __forceinline__ float bf2f(unsigned short u) {
  return __uint_as_float(((unsigned int)u) << 16);
}

// ---------------- K0: weight pack (MFMA fragment order) + rmsnorm fused -----
#define N_BFIN  (6*48*512)      // 147456
#define N_BFOUT (12*12*512)     // 73728
#define N_BFXP  (2*12*4*512)    // 49152
#define N_DT    (2*RK*DI)       // 9216
#define N_PREP  (N_BFIN + N_BFOUT + N_BFXP + N_DT)   // 279552 = 1092*256
#define PREP_BLKS 1092

__global__ __launch_bounds__(256) void k_prep(
    const float* __restrict__ wip, const float* __restrict__ wop,
    const float* __restrict__ xpwf, const float* __restrict__ xpwb,
    const float* __restrict__ dtwf, const float* __restrict__ dtwb,
    unsigned short* __restrict__ bin, unsigned short* __restrict__ bout,
    unsigned short* __restrict__ bxp, float* __restrict__ wdt,
    const float* __restrict__ h, const float* __restrict__ r,
    const float* __restrict__ w, float* __restrict__ res,
    unsigned short* __restrict__ xnb) {
  int blk = blockIdx.x;
  if (blk < PREP_BLKS) {
    int i = blk * 256 + threadIdx.x;
    if (i < N_BFIN) {
      int j = i & 7, l = (i >> 3) & 63, ng = (i >> 9) % 48, ks = i / (48 * 512);
      int k = ks * 32 + (l >> 4) * 8 + j, c = ng * 16 + (l & 15);
      bin[i] = f2bf(wip[c * DM + k]);
    } else if (i < N_BFIN + N_BFOUT) {
      int t = i - N_BFIN;
      int j = t & 7, l = (t >> 3) & 63, ng = (t >> 9) % 12, ks = t / (12 * 512);
      int k = ks * 32 + (l >> 4) * 8 + j, c = ng * 16 + (l & 15);
      bout[t] = f2bf(wop[c * DI + k]);
    } else if (i < N_BFIN + N_BFOUT + N_BFXP) {
      int t = i - N_BFIN - N_BFOUT;
      int j = t & 7, l = (t >> 3) & 63, ng = (t >> 9) & 3, ks = (t >> 11) % 12;
      int dir = t / (12 * 4 * 512);
      int k = ks * 32 + (l >> 4) * 8 + j, e = ng * 16 + (l & 15);
      const float* src = dir ? xpwb : xpwf;
      bxp[t] = (e < RK + 2 * DS) ? f2bf(src[e * DI + k]) : (unsigned short)0;
    } else if (i < N_PREP) {
      int t = i - N_BFIN - N_BFOUT - N_BFXP;
      int dir = t / (RK * DI), rem = t % (RK * DI);
      int j = rem / DI, d = rem % DI;
      const float* src = dir ? dtwb : dtwf;
      wdt[t] = src[d * RK + j];
    }
  } else {
    int row = (blk - PREP_BLKS) * 4 + (threadIdx.x >> 6);
    int lane = threadIdx.x & 63;
    const float* hp = h + row * DM;
    const float* rp = r + row * DM;
    float v0 = hp[lane]       + rp[lane];
    float v1 = hp[lane + 64]  + rp[lane + 64];
    float v2 = hp[lane + 128] + rp[lane + 128];
    float ss = v0 * v0 + v1 * v1 + v2 * v2;
    #pragma unroll
    for (int o = 32; o; o >>= 1) ss += __shfl_xor(ss, o);
    float inv = rsqrtf(ss * (1.f / DM) + 1e-5f);
    float* rr = res + row * DM;
    unsigned short* xo = xnb + row * DM;
    rr[lane] = v0; rr[lane + 64] = v1; rr[lane + 128] = v2;
    xo[lane]       = f2bf(v0 * inv * w[lane]);
    xo[lane + 64]  = f2bf(v1 * inv * w[lane + 64]);
    xo[lane + 128] = f2bf(v2 * inv * w[lane + 128]);
  }
}

// ---------------- K2: in_proj via MFMA -> bf16 xhb, zb ----------------
__global__ __launch_bounds__(64) void k_inproj(
    const unsigned short* __restrict__ xnb, const unsigned short* __restrict__ bin,
    unsigned short* __restrict__ xhb, unsigned short* __restrict__ zb) {
  int l = threadIdx.x;
  int row0 = blockIdx.x * 16;
  int ng0 = blockIdx.y * 4;
  const unsigned short* arow = xnb + (size_t)(row0 + (l & 15)) * DM + ((l >> 4) * 8);
  f32x4 acc[4];
  #pragma unroll
  for (int g = 0; g < 4; g++) acc[g] = (f32x4){0.f, 0.f, 0.f, 0.f};
  #pragma unroll
  for (int ks = 0; ks < 6; ks++) {
    bf16x8 a = *reinterpret_cast<const bf16x8*>(arow + ks * 32);
    #pragma unroll
    for (int g = 0; g < 4; g++) {
      bf16x8 b = *reinterpret_cast<const bf16x8*>(bin + ((size_t)(ks * 48 + ng0 + g) * 64 + l) * 8);
      acc[g] = __builtin_amdgcn_mfma_f32_16x16x32_bf16(a, b, acc[g], 0, 0, 0);
    }
  }
  int rbase = row0 + (l >> 4) * 4;
  #pragma unroll
  for (int g = 0; g < 4; g++) {
    int col = (ng0 + g) * 16 + (l & 15);
    unsigned short* dst = (col < DI) ? (xhb + col) : (zb + (col - DI));
    #pragma unroll
    for (int r = 0; r < 4; r++) dst[(size_t)(rbase + r) * DI] = f2bf(acc[g][r]);
  }
}

// ---------------- K3: conv + SiLU -> xcb (row-major) + xcT (chain-major) ----
// grid (64 s-tiles, 3 d-tiles, 4 zbi) = 768 blocks, 256 thr
__global__ __launch_bounds__(256) void k_conv(
    const unsigned short* __restrict__ xhb,
    const float* __restrict__ cwf, const float* __restrict__ cbf,
    const float* __restrict__ cwb, const float* __restrict__ cbb,
    unsigned short* __restrict__ xcb, unsigned short* __restrict__ xcT) {
  __shared__ unsigned short tile[CD][CSTILE + 4];   // stride 36 ushort
  int zbi = blockIdx.z;               // dir*2 + b
  int dir = zbi >> 1, b = zbi & 1;
  int d0 = blockIdx.y * CD;
  int s0 = blockIdx.x * CSTILE;
  const float* cw = dir ? cwb : cwf;
  const float* cb = dir ? cbb : cbf;
  #pragma unroll
  for (int it = 0; it < CD * CSTILE / 256; it++) {
    int o = it * 256 + threadIdx.x;
    int dl = o & (CD - 1);            // consecutive threads -> consecutive d
    int s = o >> 7;
    int d = d0 + dl, sg = s0 + s;
    float acc = cb[d];
    #pragma unroll
    for (int k = 0; k < 4; k++) {
      int sp = sg - 3 + k;
      if (sp >= 0) {
        int mr = b * LL + (dir ? (LL - 1 - sp) : sp);
        acc += cw[d * 4 + k] * bf2f(xhb[(size_t)mr * DI + d]);
      }
    }
    unsigned short v = f2bf(siluf(acc));
    xcb[(size_t)(zbi * LL + sg) * DI + d] = v;
    tile[dl][s] = v;
  }
  __syncthreads();
  #pragma unroll
  for (int it = 0; it < CD * (CSTILE / 4) / 256; it++) {
    int o = it * 256 + threadIdx.x;
    int q = o & 7, dl = o >> 3;       // 8 lanes cover one d's 32 s -> 64B runs
    ushort4 v = *reinterpret_cast<const ushort4*>(&tile[dl][q * 4]);
    *reinterpret_cast<ushort4*>(xcT + ((size_t)(zbi * DI) + d0 + dl) * LL + s0 + q * 4) = v;
  }
}

// ---------------- K4: x_proj MFMA + dt(->dtT chain-major)/B/C fused ---------
__global__ __launch_bounds__(128) void k_xpmm(
    const unsigned short* __restrict__ xcb, const unsigned short* __restrict__ bxp,
    const float* __restrict__ wdt_all,
    const float* __restrict__ dtbf, const float* __restrict__ dtbb,
    float* __restrict__ dtT, float* __restrict__ Bm, float* __restrict__ Cm) {
  __shared__ float xd[16][48];
  int l = threadIdx.x & 63, w = threadIdx.x >> 6;
  int dir = blockIdx.y;
  int row0 = blockIdx.x * 16;
  const unsigned short* arow = xcb + (size_t)(dir * NROW + row0 + (l & 15)) * DI + ((l >> 4) * 8);
  const unsigned short* wb = bxp + (size_t)dir * 12 * 4 * 512;
  f32x4 acc[2];
  acc[0] = (f32x4){0.f, 0.f, 0.f, 0.f};
  acc[1] = (f32x4){0.f, 0.f, 0.f, 0.f};
  #pragma unroll
  for (int ks = 0; ks < 12; ks++) {
    bf16x8 a = *reinterpret_cast<const bf16x8*>(arow + ks * 32);
    #pragma unroll
    for (int g = 0; g < 2; g++) {
      int ng = w * 2 + g;
      bf16x8 b = *reinterpret_cast<const bf16x8*>(wb + ((size_t)(ks * 4 + ng) * 64 + l) * 8);
      acc[g] = __builtin_amdgcn_mfma_f32_16x16x32_bf16(a, b, acc[g], 0, 0, 0);
    }
  }
  int rbase = (l >> 4) * 4;
  #pragma unroll
  for (int g = 0; g < 2; g++) {
    int col = (w * 2 + g) * 16 + (l & 15);
    #pragma unroll
    for (int r = 0; r < 4; r++) xd[rbase + r][col] = acc[g][r];
  }
  __syncthreads();
  const float* wdt = wdt_all + dir * RK * DI;
  const float* dtb = dir ? dtbb : dtbf;
  int t = threadIdx.x;
  int b = row0 >> 11, sloc = row0 & (LL - 1);
  int zbi = dir * 2 + b;
  // dt phase: each thread owns 3 d's, computes 16 s values, writes 64B runs
  #pragma unroll
  for (int dd = 0; dd < 3; dd++) {
    int d = dd * 128 + t;
    float bias = dtb[d];
    float a[16];
    #pragma unroll
    for (int r = 0; r < 16; r++) {
      float acc2 = bias;
      #pragma unroll
      for (int j = 0; j < RK; j++) acc2 = __fmaf_rn(xd[r][j], wdt[j * DI + d], acc2);
      a[r] = (acc2 > 20.f) ? acc2 : log1pf(__expf(acc2));
    }
    float* dst = dtT + ((size_t)(zbi * DI) + d) * LL + sloc;
    #pragma unroll
    for (int q = 0; q < 4; q++)
      *reinterpret_cast<float4*>(dst + q * 4) =
          make_float4(a[q*4], a[q*4+1], a[q*4+2], a[q*4+3]);
  }
  // B/C: 16 rows x 32
  #pragma unroll
  for (int i = 0; i < 4; i++) {
    int idx = i * 128 + t;
    int row = idx / 32, j = idx % 32;
    float v = xd[row][RK + j];
    if (j < DS) Bm[(size_t)(dir * NROW + row0 + row) * DS + j] = v;
    else        Cm[(size_t)(dir * NROW + row0 + row) * DS + (j - DS)] = v;
  }
}

// ---------------- S1: per-chunk local scan (chain-major streams) ------------
__global__ __launch_bounds__(128) void k_scan1(
    const float* __restrict__ dtT, const unsigned short* __restrict__ xcT,
    const float* __restrict__ Bm,
    const float* __restrict__ Alf, const float* __restrict__ Alb,
    float* __restrict__ S, float* __restrict__ P) {
  int zb = blockIdx.z;
  int dir = zb >> 1;
  int d = blockIdx.x * 128 + threadIdx.x;
  int c = blockIdx.y;
  const float* Al = dir ? Alb : Alf;
  float Av[DS];
  {
    const float4* ap = reinterpret_cast<const float4*>(Al + d * DS);
    #pragma unroll
    for (int q = 0; q < 4; q++) {
      float4 a = ap[q];
      Av[4*q+0] = -__expf(a.x); Av[4*q+1] = -__expf(a.y);
      Av[4*q+2] = -__expf(a.z); Av[4*q+3] = -__expf(a.w);
    }
  }
  const float4* dt4 = reinterpret_cast<const float4*>(dtT + ((size_t)(zb * DI) + d) * LL + c * CLEN);
  const ushort4* xc4 = reinterpret_cast<const ushort4*>(xcT + ((size_t)(zb * DI) + d) * LL + c * CLEN);
  int rowbase = zb * LL + c * CLEN;
  const float4* Bp4 = reinterpret_cast<const float4*>(Bm + (size_t)rowbase * DS);
  float h[DS];
  #pragma unroll
  for (int n = 0; n < DS; n++) h[n] = 0.f;
  float sdt = 0.f;
  #pragma unroll 2
  for (int s4 = 0; s4 < CLEN / 4; s4++) {
    float4 dq = dt4[s4];
    ushort4 xq = xc4[s4];
    float dts[4] = {dq.x, dq.y, dq.z, dq.w};
    float xs[4]  = {bf2f(xq.x), bf2f(xq.y), bf2f(xq.z), bf2f(xq.w)};
    #pragma unroll
    for (int k = 0; k < 4; k++) {
      int s = s4 * 4 + k;
      float4 B0 = Bp4[s*4+0], B1 = Bp4[s*4+1], B2 = Bp4[s*4+2], B3 = Bp4[s*4+3];
      float Bv[DS] = {B0.x,B0.y,B0.z,B0.w, B1.x,B1.y,B1.z,B1.w,
                      B2.x,B2.y,B2.z,B2.w, B3.x,B3.y,B3.z,B3.w};
      float dtv = dts[k];
      float dtx = dtv * xs[k];
      sdt += dtv;
      #pragma unroll
      for (int n = 0; n < DS; n++) {
        float dA = __expf(dtv * Av[n]);
        h[n] = __fmaf_rn(dA, h[n], dtx * Bv[n]);
      }
    }
  }
  size_t base = ((size_t)(zb * NCH + c) * DI + d) * DS;
  float4* Sp = reinterpret_cast<float4*>(S + base);
  float4* Pp = reinterpret_cast<float4*>(P + base);
  #pragma unroll
  for (int q = 0; q < 4; q++) {
    Sp[q] = make_float4(h[4*q+0], h[4*q+1], h[4*q+2], h[4*q+3]);
    Pp[q] = make_float4(__expf(Av[4*q+0]*sdt), __expf(Av[4*q+1]*sdt),
                        __expf(Av[4*q+2]*sdt), __expf(Av[4*q+3]*sdt));
  }
}

// ---------------- S2: combine carries across chunks (in-place: S -> Hin) ---
__global__ __launch_bounds__(256) void k_scan2(
    float* __restrict__ S, const float* __restrict__ P) {
  int g = blockIdx.x * 256 + threadIdx.x;
  int zb = g / (DI * DS);
  int rem = g % (DI * DS);
  const int stride = DI * DS;
  size_t base = (size_t)zb * NCH * stride + rem;
  float carry = 0.f;
  for (int c0 = 0; c0 < NCH; c0 += 8) {
    float p8[8], s8[8];
    #pragma unroll
    for (int j = 0; j < 8; j++) {
      p8[j] = P[base + (size_t)(c0 + j) * stride];
      s8[j] = S[base + (size_t)(c0 + j) * stride];
    }
    #pragma unroll
    for (int j = 0; j < 8; j++) {
      S[base + (size_t)(c0 + j) * stride] = carry;
      carry = __fmaf_rn(p8[j], carry, s8[j]);
    }
  }
}

// ---------------- S3: final per-chunk scan + y (bf16 out) ----------------
__global__ __launch_bounds__(128) void k_scan3(
    const float* __restrict__ dtT, const unsigned short* __restrict__ xcT,
    const float* __restrict__ Bm, const float* __restrict__ Cm,
    const unsigned short* __restrict__ zb_, const float* __restrict__ Hin,
    const float* __restrict__ Alf, const float* __restrict__ Alb,
    const float* __restrict__ Df, const float* __restrict__ Db,
    unsigned short* __restrict__ yb) {
  int zbi = blockIdx.z;
  int dir = zbi >> 1, b = zbi & 1;
  int d = blockIdx.x * 128 + threadIdx.x;
  int c = blockIdx.y;
  const float* Al = dir ? Alb : Alf;
  const float* Dp = dir ? Db : Df;
  float Av[DS];
  {
    const float4* ap = reinterpret_cast<const float4*>(Al + d * DS);
    #pragma unroll
    for (int q = 0; q < 4; q++) {
      float4 a = ap[q];
      Av[4*q+0] = -__expf(a.x); Av[4*q+1] = -__expf(a.y);
      Av[4*q+2] = -__expf(a.z); Av[4*q+3] = -__expf(a.w);
    }
  }
  float Dv = Dp[d];
  const float4* dt4 = reinterpret_cast<const float4*>(dtT + ((size_t)(zbi * DI) + d) * LL + c * CLEN);
  const ushort4* xc4 = reinterpret_cast<const ushort4*>(xcT + ((size_t)(zbi * DI) + d) * LL + c * CLEN);
  int rowbase = zbi * LL + c * CLEN;
  const float4* Bp4 = reinterpret_cast<const float4*>(Bm + (size_t)rowbase * DS);
  const float4* Cp4 = reinterpret_cast<const float4*>(Cm + (size_t)rowbase * DS);
  size_t base = ((size_t)(zbi * NCH + c) * DI + d) * DS;
  float h[DS];
  {
    const float4* hp = reinterpret_cast<const float4*>(Hin + base);
    #pragma unroll
    for (int q = 0; q < 4; q++) {
      float4 a = hp[q];
      h[4*q+0] = a.x; h[4*q+1] = a.y; h[4*q+2] = a.z; h[4*q+3] = a.w;
    }
  }
  #pragma unroll 2
  for (int s4 = 0; s4 < CLEN / 4; s4++) {
    float4 dq = dt4[s4];
    ushort4 xq = xc4[s4];
    float dts[4] = {dq.x, dq.y, dq.z, dq.w};
    float xs[4]  = {bf2f(xq.x), bf2f(xq.y), bf2f(xq.z), bf2f(xq.w)};
    #pragma unroll
    for (int k = 0; k < 4; k++) {
      int s = s4 * 4 + k;
      float4 B0 = Bp4[s*4+0], B1 = Bp4[s*4+1], B2 = Bp4[s*4+2], B3 = Bp4[s*4+3];
      float Bv[DS] = {B0.x,B0.y,B0.z,B0.w, B1.x,B1.y,B1.z,B1.w,
                      B2.x,B2.y,B2.z,B2.w, B3.x,B3.y,B3.z,B3.w};
      float4 C0 = Cp4[s*4+0], C1 = Cp4[s*4+1], C2 = Cp4[s*4+2], C3 = Cp4[s*4+3];
      float Cv[DS] = {C0.x,C0.y,C0.z,C0.w, C1.x,C1.y,C1.z,C1.w,
                      C2.x,C2.y,C2.z,C2.w, C3.x,C3.y,C3.z,C3.w};
      float dtv = dts[k];
      float xv = xs[k];
      float dtx = dtv * xv;
      float acc = xv * Dv;
      #pragma unroll
      for (int n = 0; n < DS; n++) {
        float dA = __expf(dtv * Av[n]);
        h[n] = __fmaf_rn(dA, h[n], dtx * Bv[n]);
        acc = __fmaf_rn(h[n], Cv[n], acc);
      }
      int sg = c * CLEN + s;
      int mr = b * LL + (dir ? (LL - 1 - sg) : sg);
      float zv = bf2f(zb_[(size_t)mr * DI + d]);
      yb[(size_t)(rowbase + s) * DI + d] = f2bf(acc * siluf(zv));
    }
  }
}

// ---------------- K5: out_proj via MFMA (fused y_f + rev(y_b)) ---------
__global__ __launch_bounds__(64) void k_outproj(
    const unsigned short* __restrict__ yb, const unsigned short* __restrict__ bout,
    float* __restrict__ out) {
  int l = threadIdx.x;
  int row0 = blockIdx.x * 16;
  int ng0 = blockIdx.y * 2;
  int row = row0 + (l & 15);
  int b = row >> 11, ll = row & (LL - 1);
  const unsigned short* yf = yb + (size_t)(b * LL + ll) * DI + (l >> 4) * 8;
  const unsigned short* yr = yb + (size_t)((2 + b) * LL + (LL - 1 - ll)) * DI + (l >> 4) * 8;
  f32x4 acc[2];
  acc[0] = (f32x4){0.f, 0.f, 0.f, 0.f};
  acc[1] = (f32x4){0.f, 0.f, 0.f, 0.f};
  #pragma unroll
  for (int ks = 0; ks < 12; ks++) {
    bf16x8 f8 = *reinterpret_cast<const bf16x8*>(yf + ks * 32);
    bf16x8 g8 = *reinterpret_cast<const bf16x8*>(yr + ks * 32);
    bf16x8 a;
    #pragma unroll
    for (int j = 0; j < 8; j++)
      a[j] = (short)f2bf(bf2f((unsigned short)f8[j]) + bf2f((unsigned short)g8[j]));
    #pragma unroll
    for (int g = 0; g < 2; g++) {
      bf16x8 bb = *reinterpret_cast<const bf16x8*>(bout + ((size_t)(ks * 12 + ng0 + g) * 64 + l) * 8);
      acc[g] = __builtin_amdgcn_mfma_f32_16x16x32_bf16(a, bb, acc[g], 0, 0, 0);
    }
  }
  int rbase = row0 + (l >> 4) * 4;
  #pragma unroll
  for (int g = 0; g < 2; g++) {
    int col = (ng0 + g) * 16 + (l & 15);
    #pragma unroll
    for (int r = 0; r < 4; r++) out[(size_t)(rbase + r) * DM + col] = acc[g][r];
  }
}

extern "C" void kernel_launch(void* const* d_in, const int* in_sizes, int n_in,
                              void* d_out, int out_size, void* d_ws, size_t ws_size,
                              hipStream_t stream) {
  const float* hid  = (const float*)d_in[0];
  const float* res  = (const float*)d_in[1];
  const float* nw   = (const float*)d_in[2];
  const float* wip  = (const float*)d_in[3];
  const float* wop  = (const float*)d_in[4];
  const float* cwf  = (const float*)d_in[5];
  const float* cbf  = (const float*)d_in[6];
  const float* xpwf = (const float*)d_in[7];
  const float* dtwf = (const float*)d_in[8];
  const float* dtbf = (const float*)d_in[9];
  const float* Alf  = (const float*)d_in[10];
  const float* Df   = (const float*)d_in[11];
  const float* cwb  = (const float*)d_in[12];
  const float* cbb  = (const float*)d_in[13];
  const float* xpwb = (const float*)d_in[14];
  const float* dtwb = (const float*)d_in[15];
  const float* dtbb = (const float*)d_in[16];
  const float* Alb  = (const float*)d_in[17];
  const float* Db   = (const float*)d_in[18];

  float* out_p  = (float*)d_out;                  // (B,L,192)
  float* resid  = out_p + NROW * DM;              // (B,L,192)

  float* ws = (float*)d_ws;
  // f32 arrays
  float* dtT  = ws;                          // 2*NROW*DI
  float* Bm   = dtT  + 2 * NROW * DI;        // 2*NROW*DS
  float* Cm   = Bm   + 2 * NROW * DS;
  float* S    = Cm   + 2 * NROW * DS;        // 2*BB*NCH*DI*DS
  float* P    = S    + 2 * BB * NCH * DI * DS;
  float* wdt  = P    + 2 * BB * NCH * DI * DS;   // N_DT
  // bf16 arrays
  unsigned short* xnb = (unsigned short*)(wdt + N_DT);   // NROW*DM
  unsigned short* xhb = xnb + NROW * DM;                 // NROW*DI
  unsigned short* zb  = xhb + NROW * DI;                 // NROW*DI
  unsigned short* xcb = zb  + NROW * DI;                 // 2*NROW*DI
  unsigned short* xcT = xcb + 2 * NROW * DI;             // 2*NROW*DI
  unsigned short* yb  = xcT + 2 * NROW * DI;             // 2*NROW*DI
  unsigned short* bin = yb  + 2 * NROW * DI;             // N_BFIN
  unsigned short* bout = bin + N_BFIN;                   // N_BFOUT
  unsigned short* bxp  = bout + N_BFOUT;                 // N_BFXP

  k_prep<<<PREP_BLKS + NROW / 4, 256, 0, stream>>>(wip, wop, xpwf, xpwb, dtwf, dtwb,
                                                   bin, bout, bxp, wdt,
                                                   hid, res, nw, resid, xnb);
  k_inproj<<<dim3(NROW / 16, 12), 64, 0, stream>>>(xnb, bin, xhb, zb);
  k_conv<<<dim3(LL / CSTILE, DI / CD, 2 * BB), 256, 0, stream>>>(xhb, cwf, cbf, cwb, cbb, xcb, xcT);
  k_xpmm<<<dim3(NROW / 16, 2), 128, 0, stream>>>(xcb, bxp, wdt, dtbf, dtbb, dtT, Bm, Cm);
  k_scan1<<<dim3(DI / 128, NCH, 2 * BB), 128, 0, stream>>>(dtT, xcT, Bm, Alf, Alb, S, P);
  k_scan2<<<(2 * BB * DI * DS) / 256, 256, 0, stream>>>(S, P);
  k_scan3<<<dim3(DI / 128, NCH, 2 * BB), 128, 0, stream>>>(dtT, xcT, Bm, Cm, zb, S,
                                                           Alf, Alb, Df, Db, yb);
  k_outproj<<<dim3(NROW / 16, 6), 64, 0, stream>>>(yb, bout, out_p);
}